// Round 13
// baseline (2164.618 us; speedup 1.0000x reference)
//
#include <hip/hip_runtime.h>
#include <math.h>

namespace {
constexpr int T_ = 32, B_ = 32, H_ = 512, S_ = 512;
constexpr int BH = B_ * H_;     // 16384
constexpr int LSTM_NWG = 256;
// ws float offsets
constexpr size_t O_EMBS = 0;                          // [T*B][H]
constexpr size_t O_H0   = O_EMBS + (size_t)T_ * BH;   // [2][BH]
constexpr size_t O_H1   = O_H0 + 2 * BH;              // [2][BH]
constexpr size_t O_GC   = O_H1 + 2 * BH;              // gamma [1024][512]
constexpr size_t O_CTC  = O_GC + (size_t)1024 * 512;  // ct
constexpr size_t O_OCV  = O_CTC + (size_t)1024 * 512; // out_conv
}

// Monotonic barrier state (zero-init at load, survives graph replays, immune
// to 0xAA ws poison). Used only by k_lstm.
__device__ unsigned g_arrive[LSTM_NWG] = {};
__device__ unsigned g_go = 0;

static __device__ __forceinline__ float sigm(float x) { return 1.0f / (1.0f + expf(-x)); }
static __device__ __forceinline__ float dot4(float4 a, float4 b) {
  return a.x * b.x + a.y * b.y + a.z * b.z + a.w * b.w;
}
static __device__ __forceinline__ void fma4(float4& a, float s, float4 x) {
  a.x += s * x.x; a.y += s * x.y; a.z += s * x.z; a.w += s * x.w;
}
static __device__ __forceinline__ void scale_fma4(float4& a, float f, float e, float4 x) {
  a.x = a.x * f + e * x.x; a.y = a.y * f + e * x.y;
  a.z = a.z * f + e * x.z; a.w = a.w * f + e * x.w;
}

// Fence-free grid barrier (validated round 7). Cross-WG data moves via sc1
// accesses that bypass L2; barrier needs only vmcnt drain + flag atomics.
static __device__ __forceinline__ void grid_barrier_light(unsigned target) {
  asm volatile("s_waitcnt vmcnt(0)" ::: "memory");  // drain own sc1 h-stores
  __syncthreads();
  if (threadIdx.x == 0)
    __hip_atomic_store(&g_arrive[blockIdx.x], target, __ATOMIC_RELAXED,
                       __HIP_MEMORY_SCOPE_AGENT);
  if (blockIdx.x == 0) {
    for (int i = threadIdx.x; i < LSTM_NWG; i += 512)
      while (__hip_atomic_load(&g_arrive[i], __ATOMIC_RELAXED,
                               __HIP_MEMORY_SCOPE_AGENT) < target)
        __builtin_amdgcn_s_sleep(1);
    __syncthreads();
    if (threadIdx.x == 0)
      __hip_atomic_store(&g_go, target, __ATOMIC_RELAXED,
                         __HIP_MEMORY_SCOPE_AGENT);
  }
  if (threadIdx.x == 0)
    while (__hip_atomic_load(&g_go, __ATOMIC_RELAXED,
                             __HIP_MEMORY_SCOPE_AGENT) < target)
      __builtin_amdgcn_s_sleep(1);
  __syncthreads();
  asm volatile("" ::: "memory");   // compiler barrier: no load hoisting
}

// ---------------- K1: init state + embedding gather ----------------
__global__ __launch_bounds__(512)
void k_init(const int* __restrict__ inputs, const float* __restrict__ h0in,
            const float* __restrict__ emb, float* __restrict__ ws) {
  const int g = blockIdx.x, tid = threadIdx.x;
  const int gid = g * 512 + tid;
  // Ping parity: layer-0 initial h in ping 0; layer-1 initial h in ping 1.
  if (gid < BH) {
    ws[O_H0 + gid]      = h0in[gid];
    ws[O_H1 + BH + gid] = h0in[BH + gid];
  }
#pragma unroll
  for (int r = 0; r < 4; ++r) {
    const int tb = g * 4 + r;
    ws[O_EMBS + (size_t)tb * H_ + tid] = emb[(size_t)inputs[tb] * H_ + tid];
  }
}

// ---------------- K2: persistent LSTM chain, phase-split MAC ----------------
// 256 WGs x 512 threads, 1 WG/CU. WG = (cell = g>>7, quad q = g&127) owning
// cols j = q*4..+3. Thread = (jj = tid&3 col, gt = (tid>>2)&3 gate,
// ks = tid>>4 in [0,32) K-window of 16). Each thread: ONE gate row x 16-K
// window x all 32 b -> acc[32]. Weights in LDS permanently (wlds[16][1028],
// row = col*4+gate, cols 0..511 = Wih, 512..1023 = Whh); per phase only
// 4 weight-float4 live (16 regs; 32 if both phases hoisted).
// Register bill: w 32 + acc 32 + staging temps ~32 + addr ~12 = ~110 < 128.
// Round 9-12 lesson: demand must sit COMFORTABLY under the immovable
// 128-VGPR cap or the RA spills the big arrays to scratch (GBs of HBM
// traffic); round-12's gate-pair map hit ~140 via hoisted weights and spilled.
__global__ __launch_bounds__(512)
void k_lstm(const float* __restrict__ W_ih, const float* __restrict__ W_hh,
            const float* __restrict__ b_ih, const float* __restrict__ b_hh,
            const float* __restrict__ c0in, float* __restrict__ out,
            float* __restrict__ ws) {
  const int g = blockIdx.x, tid = threadIdx.x;
  const int cell = g >> 7, q = g & 127;
  const int jj = tid & 3, gt = (tid >> 2) & 3, ks = tid >> 4;
  const int row = jj * 4 + gt;         // 0..15, matches wlds/red row layout
  float* EMBS = ws + O_EMBS;
  float* H0 = ws + O_H0;
  float* H1 = ws + O_H1;

  __shared__ __align__(16) float wlds[16 * 1028];   // weights, persistent, 66 KB
  __shared__ __align__(16) float stg[16512];        // x / h / red, 66 KB
  __shared__ float gates[512];

  // ---- one-time: weights into LDS (persistent). Per pass: 16 rows x 512
  // floats = 2048 float4 -> i<4. lrow = col*4 + gate; pass0 = Wih half
  // (offset 0), pass1 = Whh half (offset 512).
  {
    const float* Wih = W_ih + (size_t)cell * 4 * H_ * H_;
    const float* Whh = W_hh + (size_t)cell * 4 * H_ * H_;
#pragma unroll
    for (int pass = 0; pass < 2; ++pass) {
      const float* Wsrc = pass ? Whh : Wih;
#pragma unroll
      for (int i = 0; i < 4; ++i) {
        const int d4 = tid + i * 512;          // float4 idx 0..2047
        const int lrow = d4 >> 7;              // 0..15 = col*4 + gate
        const int f4 = d4 & 127;               // 0..127
        const int rr = lrow & 3, jx = lrow >> 2;
        const float4 v = *(const float4*)&Wsrc[((size_t)rr * H_ + q * 4 + jx) * H_ + f4 * 4];
        *(float4*)&wlds[lrow * 1028 + pass * 512 + f4 * 4] = v;
      }
    }
  }
  // ---- one-time: bias sums + c-state for finalize threads (tid < 128) ----
  float creg = 0.f, bs0 = 0.f, bs1 = 0.f, bs2 = 0.f, bs3 = 0.f;
  if (tid < 128) {
    const int fj = tid >> 5, fb = tid & 31;
    const int fjo = q * 4 + fj;
    creg = c0in[cell * BH + fb * H_ + fjo];
    const float* bi = b_ih + (size_t)cell * 4 * H_;
    const float* bh = b_hh + (size_t)cell * 4 * H_;
    bs0 = bi[0 * H_ + fjo] + bh[0 * H_ + fjo];
    bs1 = bi[1 * H_ + fjo] + bh[1 * H_ + fjo];
    bs2 = bi[2 * H_ + fjo] + bh[2 * H_ + fjo];
    bs3 = bi[3 * H_ + fjo] + bh[3 * H_ + fjo];
  }
  __syncthreads();   // wlds visible to all

  unsigned bar = __hip_atomic_load(&g_go, __ATOMIC_RELAXED,
                                   __HIP_MEMORY_SCOPE_AGENT);

  for (int s = 0; s <= T_; ++s) {
    const int pi = s & 1, qi = pi ^ 1;
    const bool act = cell ? (s >= 1) : (s < T_);   // WG-uniform
    if (act) {
      float acc[32];

      // ======== phase X: stage x operand, MAC with x-half weights ========
      if (cell == 0) {   // x = EMBS[s] (normal cached loads, L2-hot)
        const float* src = EMBS + (size_t)s * BH;
#pragma unroll 4
        for (int i = 0; i < 8; ++i) {
          const int d = tid + i * 512;
          const int b = d >> 7, k4 = d & 127;
          const float4 v = *(const float4*)(src + b * 512 + k4 * 4);
          *(float4*)&stg[(k4 >> 2) * 516 + b * 16 + (k4 & 3) * 4] = v;
        }
      } else {           // x = H0[pi] (sc1 coherent)
        const float* src = H0 + pi * BH;
#pragma unroll 4
        for (int i = 0; i < 8; ++i) {
          const int d = tid + i * 512;
          const int b = d >> 7, k4 = d & 127;
          const float* p = src + b * 512 + k4 * 4;
          const unsigned long long u0 = __hip_atomic_load(
              (const unsigned long long*)p, __ATOMIC_RELAXED, __HIP_MEMORY_SCOPE_AGENT);
          const unsigned long long u1 = __hip_atomic_load(
              (const unsigned long long*)(p + 2), __ATOMIC_RELAXED, __HIP_MEMORY_SCOPE_AGENT);
          float4 v;
          v.x = __uint_as_float((unsigned)u0); v.y = __uint_as_float((unsigned)(u0 >> 32));
          v.z = __uint_as_float((unsigned)u1); v.w = __uint_as_float((unsigned)(u1 >> 32));
          *(float4*)&stg[(k4 >> 2) * 516 + b * 16 + (k4 & 3) * 4] = v;
        }
      }
      __syncthreads();
      {
        const float* wb = &wlds[row * 1028 + ks * 16];   // x-half weights
        const float4 w0 = *(const float4*)(wb);
        const float4 w1 = *(const float4*)(wb + 4);
        const float4 w2 = *(const float4*)(wb + 8);
        const float4 w3 = *(const float4*)(wb + 12);
#pragma unroll
        for (int bi = 0; bi < 32; ++bi) {
          const float* hp = &stg[ks * 516 + bi * 16];
          const float4 h0 = *(const float4*)(hp);
          const float4 h1 = *(const float4*)(hp + 4);
          const float4 h2 = *(const float4*)(hp + 8);
          const float4 h3 = *(const float4*)(hp + 12);
          acc[bi] = dot4(h0, w0) + dot4(h1, w1) + dot4(h2, w2) + dot4(h3, w3);
        }
      }
      __syncthreads();   // stg consumed; restage with h

      // ======== phase H: stage h operand, MAC with h-half weights ========
      {
        const float* src = (cell ? H1 : H0) + pi * BH;
#pragma unroll 4
        for (int i = 0; i < 8; ++i) {
          const int d = tid + i * 512;
          const int b = d >> 7, k4 = d & 127;
          const float* p = src + b * 512 + k4 * 4;
          const unsigned long long u0 = __hip_atomic_load(
              (const unsigned long long*)p, __ATOMIC_RELAXED, __HIP_MEMORY_SCOPE_AGENT);
          const unsigned long long u1 = __hip_atomic_load(
              (const unsigned long long*)(p + 2), __ATOMIC_RELAXED, __HIP_MEMORY_SCOPE_AGENT);
          float4 v;
          v.x = __uint_as_float((unsigned)u0); v.y = __uint_as_float((unsigned)(u0 >> 32));
          v.z = __uint_as_float((unsigned)u1); v.w = __uint_as_float((unsigned)(u1 >> 32));
          *(float4*)&stg[(k4 >> 2) * 516 + b * 16 + (k4 & 3) * 4] = v;
        }
      }
      __syncthreads();
      {
        const float* wb = &wlds[row * 1028 + 512 + ks * 16];   // h-half weights
        const float4 w0 = *(const float4*)(wb);
        const float4 w1 = *(const float4*)(wb + 4);
        const float4 w2 = *(const float4*)(wb + 8);
        const float4 w3 = *(const float4*)(wb + 12);
#pragma unroll
        for (int bi = 0; bi < 32; ++bi) {
          const float* hp = &stg[ks * 516 + bi * 16];
          const float4 h0 = *(const float4*)(hp);
          const float4 h1 = *(const float4*)(hp + 4);
          const float4 h2 = *(const float4*)(hp + 8);
          const float4 h3 = *(const float4*)(hp + 12);
          acc[bi] += dot4(h0, w0) + dot4(h1, w1) + dot4(h2, w2) + dot4(h3, w3);
        }
      }
      __syncthreads();   // stg consumed; stg becomes red

      // ---- K-reduction: red[ks][row:16][b:32], stride 516 ----
      float* red = stg;
#pragma unroll
      for (int c = 0; c < 8; ++c) {
        *(float4*)&red[ks * 516 + row * 32 + c * 4] =
            make_float4(acc[c * 4], acc[c * 4 + 1],
                        acc[c * 4 + 2], acc[c * 4 + 3]);
      }
      __syncthreads();
      {
        const int rrow = tid >> 5, bb = tid & 31;
        float sum = 0.f;
#pragma unroll
        for (int k2 = 0; k2 < 32; ++k2) sum += red[k2 * 516 + rrow * 32 + bb];
        gates[rrow * 32 + bb] = sum;
      }
      __syncthreads();

      // ---- finalize: 128 threads = (fj in 4 cols, fb in 32 b) ----
      if (tid < 128) {
        const int fj = tid >> 5, fb = tid & 31;
        const int fjo = q * 4 + fj;
        const float gi  = gates[(fj * 4 + 0) * 32 + fb] + bs0;
        const float gf  = gates[(fj * 4 + 1) * 32 + fb] + bs1;
        const float gg  = gates[(fj * 4 + 2) * 32 + fb] + bs2;
        const float go_ = gates[(fj * 4 + 3) * 32 + fb] + bs3;
        const float cn = sigm(gf) * creg + sigm(gi) * tanhf(gg);
        const float hn = sigm(go_) * tanhf(cn);
        creg = cn;
        float* Hs = cell ? H1 : H0;
        __hip_atomic_store(&Hs[qi * BH + fb * H_ + fjo], hn,
                           __ATOMIC_RELAXED, __HIP_MEMORY_SCOPE_AGENT);
        if (cell)  // stash h1(t) rows (XH) in out[t]
          out[((size_t)(s - 1) * B_ + fb) * H_ + fjo] = hn;
        if (!cell && s == T_ - 1) {   // final h0/c0
          out[(size_t)T_ * BH + fb * H_ + fjo]          = hn;
          out[(size_t)T_ * BH + 2 * BH + fb * H_ + fjo] = cn;
        }
        if (cell && s == T_) {        // final h1/c1
          out[(size_t)T_ * BH + BH + fb * H_ + fjo]     = hn;
          out[(size_t)T_ * BH + 3 * BH + fb * H_ + fjo] = cn;
        }
      }
    }
    if (s < T_) grid_barrier_light(++bar);
  }
}

// ---------------- tiled GEMM: C[m][n] = ep(A[m][:] . W[n][:] + bias[n]) ----
template<bool TANH, bool RES>
__global__ __launch_bounds__(256)
void k_gemm(const float* __restrict__ A1, const float* __restrict__ A2,
            const float* __restrict__ W, const float* __restrict__ bias,
            const float* __restrict__ res, float* __restrict__ C, int dualA) {
  const int bid = blockIdx.x, tid = threadIdx.x;
  const int m0 = (bid & 31) * 32, n0 = (bid >> 5) * 32;
  const int tx = tid & 15, ty = tid >> 4;
  const int lr = tid >> 5, lc = tid & 31;
  const int nsteps = dualA ? 32 : 16;
  const int Krow = dualA ? 1024 : 512;
  __shared__ __align__(16) float Asm[32 * 33];
  __shared__ __align__(16) float Bsm[32 * 34];
  float acc00 = 0.f, acc01 = 0.f, acc10 = 0.f, acc11 = 0.f;

  for (int kt = 0; kt < nsteps; ++kt) {
    const float* A = (kt < 16) ? A1 : A2;
    const int ka = (kt < 16) ? kt * 32 : (kt - 16) * 32;
    const int kb = kt * 32;
    __syncthreads();
#pragma unroll
    for (int i = 0; i < 4; ++i) {
      const int row = lr + i * 8;
      Asm[row * 33 + lc] = A[(size_t)(m0 + row) * 512 + ka + lc];
      Bsm[lc * 34 + row] = W[(size_t)(n0 + row) * Krow + kb + lc];
    }
    __syncthreads();
#pragma unroll 8
    for (int k = 0; k < 32; ++k) {
      const float a0 = Asm[(ty * 2) * 33 + k];
      const float a1 = Asm[(ty * 2 + 1) * 33 + k];
      const float2 bv = *(const float2*)&Bsm[k * 34 + tx * 2];
      acc00 += a0 * bv.x; acc01 += a0 * bv.y;
      acc10 += a1 * bv.x; acc11 += a1 * bv.y;
    }
  }
  const int n = n0 + tx * 2;
  const int m = m0 + ty * 2;
  const float bx = bias[n], by = bias[n + 1];
  float v00 = acc00 + bx, v01 = acc01 + by;
  float v10 = acc10 + bx, v11 = acc11 + by;
  if (TANH) { v00 = tanhf(v00); v01 = tanhf(v01); v10 = tanhf(v10); v11 = tanhf(v11); }
  if (RES) {
    v00 += res[(size_t)m * 512 + n];       v01 += res[(size_t)m * 512 + n + 1];
    v10 += res[(size_t)(m + 1) * 512 + n]; v11 += res[(size_t)(m + 1) * 512 + n + 1];
  }
  C[(size_t)m * 512 + n] = v00;            C[(size_t)m * 512 + n + 1] = v01;
  C[(size_t)(m + 1) * 512 + n] = v10;      C[(size_t)(m + 1) * 512 + n + 1] = v11;
}

// ---------------- K4: sigmoid-gated sweep over contexts_conv ----------------
__global__ __launch_bounds__(256)
void k_sweep_conv(const float* __restrict__ ctxc, const float* __restrict__ GC,
                  float* __restrict__ CTC) {
  const int bid = blockIdx.x, tid = threadIdx.x;
  const int b = bid & 31;
  const int w = tid >> 6, lane = tid & 63;
  const float* gl = GC + (size_t)bid * H_ + lane * 8;
  const float4 g0 = *(const float4*)gl;
  const float4 g1 = *(const float4*)(gl + 4);
  float4 a0 = {0, 0, 0, 0}, a1 = {0, 0, 0, 0};
  const float* base = ctxc + (size_t)b * S_ * H_ + lane * 8;
  for (int i = 0; i < 128; ++i) {
    const int s = i * 4 + w;
    const float* xr = base + (size_t)s * H_;
    const float4 x0 = *(const float4*)(xr);
    const float4 x1 = *(const float4*)(xr + 4);
    float p = dot4(x0, g0) + dot4(x1, g1);
#pragma unroll
    for (int off = 32; off >= 1; off >>= 1) p += __shfl_xor(p, off, 64);
    const float wt = sigm(p);
    fma4(a0, wt, x0); fma4(a1, wt, x1);
  }
  __shared__ __align__(16) float part[4 * 512];
  *(float4*)&part[w * 512 + lane * 8] = a0;
  *(float4*)&part[w * 512 + lane * 8 + 4] = a1;
  __syncthreads();
  float sA = 0.f, sB = 0.f;
#pragma unroll
  for (int w8 = 0; w8 < 4; ++w8) {
    sA += part[w8 * 512 + tid];
    sB += part[w8 * 512 + 256 + tid];
  }
  CTC[(size_t)bid * H_ + tid] = sA;
  CTC[(size_t)bid * H_ + 256 + tid] = sB;
}

// ---------------- K7: online-softmax sweep over contexts ----------------
__global__ __launch_bounds__(256)
void k_sweep_att(const float* __restrict__ ctx, const float* __restrict__ GA,
                 float* __restrict__ CT) {
  const int bid = blockIdx.x, tid = threadIdx.x;
  const int b = bid & 31;
  const int w = tid >> 6, lane = tid & 63;
  const float* gl = GA + (size_t)bid * H_ + lane * 8;
  const float4 g0 = *(const float4*)gl;
  const float4 g1 = *(const float4*)(gl + 4);
  float4 a0 = {0, 0, 0, 0}, a1 = {0, 0, 0, 0};
  float m = -1e30f, l = 0.f;
  const float* base = ctx + (size_t)b * S_ * H_ + lane * 8;
  for (int i = 0; i < 128; ++i) {
    const int s = i * 4 + w;
    const float* xr = base + (size_t)s * H_;
    const float4 x0 = *(const float4*)(xr);
    const float4 x1 = *(const float4*)(xr + 4);
    float p = dot4(x0, g0) + dot4(x1, g1);
#pragma unroll
    for (int off = 32; off >= 1; off >>= 1) p += __shfl_xor(p, off, 64);
    const float m2 = fmaxf(m, p);
    const float f = expf(m - m2);
    const float e = expf(p - m2);
    l = l * f + e;
    scale_fma4(a0, f, e, x0);
    scale_fma4(a1, f, e, x1);
    m = m2;
  }
  __shared__ __align__(16) float part[4 * 512 + 8];
  *(float4*)&part[w * 512 + lane * 8] = a0;
  *(float4*)&part[w * 512 + lane * 8 + 4] = a1;
  if (lane == 0) { part[2048 + w * 2] = m; part[2048 + w * 2 + 1] = l; }
  __syncthreads();
  float M = part[2048];
#pragma unroll
  for (int w8 = 1; w8 < 4; ++w8) M = fmaxf(M, part[2048 + w8 * 2]);
  float fac[4], L = 0.f;
#pragma unroll
  for (int w8 = 0; w8 < 4; ++w8) {
    fac[w8] = expf(part[2048 + w8 * 2] - M);
    L += fac[w8] * part[2048 + w8 * 2 + 1];
  }
  const float inv = 1.0f / L;
  float sA = 0.f, sB = 0.f;
#pragma unroll
  for (int w8 = 0; w8 < 4; ++w8) {
    sA += fac[w8] * part[w8 * 512 + tid];
    sB += fac[w8] * part[w8 * 512 + 256 + tid];
  }
  CT[(size_t)bid * H_ + tid] = sA * inv;
  CT[(size_t)bid * H_ + 256 + tid] = sB * inv;
}

extern "C" void kernel_launch(void* const* d_in, const int* in_sizes, int n_in,
                              void* d_out, int out_size, void* d_ws, size_t ws_size,
                              hipStream_t stream) {
  const int*   inputs  = (const int*)d_in[0];
  const float* h0in    = (const float*)d_in[1];
  const float* c0in    = (const float*)d_in[2];
  const float* ctx     = (const float*)d_in[3];
  const float* ctxc    = (const float*)d_in[4];
  const float* emb     = (const float*)d_in[5];
  const float* W_ih    = (const float*)d_in[6];
  const float* W_hh    = (const float*)d_in[7];
  const float* b_ih    = (const float*)d_in[8];
  const float* b_hh    = (const float*)d_in[9];
  const float* Wi_att  = (const float*)d_in[10];
  const float* bi_att  = (const float*)d_in[11];
  const float* Wo_att  = (const float*)d_in[12];
  const float* bo_att  = (const float*)d_in[13];
  const float* Wi_conv = (const float*)d_in[14];
  const float* bi_conv = (const float*)d_in[15];
  const float* Wo_conv = (const float*)d_in[16];
  const float* bo_conv = (const float*)d_in[17];
  float* out = (float*)d_out;
  float* ws  = (float*)d_ws;

  float* GC  = ws + O_GC;    // gamma_conv, then gamma_att
  float* CTC = ws + O_CTC;   // ct_conv, then ct_att
  float* OCV = ws + O_OCV;   // out_conv

  k_init<<<dim3(256), dim3(512), 0, stream>>>(inputs, h0in, emb, ws);
  k_lstm<<<dim3(LSTM_NWG), dim3(512), 0, stream>>>(W_ih, W_hh, b_ih, b_hh,
                                                   c0in, out, ws);
  // gamma_conv = XH @ Wi_conv^T + bi_conv   (XH stashed in out)
  k_gemm<false, false><<<dim3(512), dim3(256), 0, stream>>>(
      out, nullptr, Wi_conv, bi_conv, nullptr, GC, 0);
  k_sweep_conv<<<dim3(1024), dim3(256), 0, stream>>>(ctxc, GC, CTC);
  // out_conv = tanh([ct_c | XH] @ Wo_conv^T + bo_conv)
  k_gemm<true, false><<<dim3(512), dim3(256), 0, stream>>>(
      CTC, out, Wo_conv, bo_conv, nullptr, OCV, 1);
  // gamma_att = OCV @ Wi_att^T + bi_att
  k_gemm<false, false><<<dim3(512), dim3(256), 0, stream>>>(
      OCV, nullptr, Wi_att, bi_att, nullptr, GC, 0);
  k_sweep_att<<<dim3(1024), dim3(256), 0, stream>>>(ctx, GC, CTC);
  // out = tanh([ct | OCV] @ Wo_att^T + bo_att) + OCV
  k_gemm<true, true><<<dim3(512), dim3(256), 0, stream>>>(
      CTC, OCV, Wo_att, bo_att, OCV, out, 1);
}

// Round 14
// 796.261 us; speedup vs baseline: 2.7185x; 2.7185x over previous
//
#include <hip/hip_runtime.h>
#include <math.h>

namespace {
constexpr int T_ = 32, B_ = 32, H_ = 512, S_ = 512;
constexpr int BH = B_ * H_;     // 16384
constexpr int LSTM_NWG = 512;
// ws float offsets
constexpr size_t O_EMBS = 0;                          // [T*B][H]
constexpr size_t O_H0   = O_EMBS + (size_t)T_ * BH;   // [2][BH]
constexpr size_t O_H1   = O_H0 + 2 * BH;              // [2][BH]
constexpr size_t O_GC   = O_H1 + 2 * BH;              // gamma [1024][512]
constexpr size_t O_CTC  = O_GC + (size_t)1024 * 512;  // ct
constexpr size_t O_OCV  = O_CTC + (size_t)1024 * 512; // out_conv
}

// Monotonic barrier state (zero-init at load, survives graph replays, immune
// to 0xAA ws poison). Used only by k_lstm.
__device__ unsigned g_arrive[LSTM_NWG] = {};
__device__ unsigned g_go = 0;

static __device__ __forceinline__ float sigm(float x) { return 1.0f / (1.0f + expf(-x)); }
static __device__ __forceinline__ float dot4(float4 a, float4 b) {
  return a.x * b.x + a.y * b.y + a.z * b.z + a.w * b.w;
}
static __device__ __forceinline__ void fma4(float4& a, float s, float4 x) {
  a.x += s * x.x; a.y += s * x.y; a.z += s * x.z; a.w += s * x.w;
}
static __device__ __forceinline__ void scale_fma4(float4& a, float f, float e, float4 x) {
  a.x = a.x * f + e * x.x; a.y = a.y * f + e * x.y;
  a.z = a.z * f + e * x.z; a.w = a.w * f + e * x.w;
}

static __device__ __forceinline__ float coh_load(const float* p) {
  return __hip_atomic_load(p, __ATOMIC_RELAXED, __HIP_MEMORY_SCOPE_AGENT);
}

// Fence-free grid barrier (validated round 7). Cross-WG data moves via sc1
// accesses that bypass L2; barrier needs only vmcnt drain + flag atomics.
static __device__ __forceinline__ void grid_barrier_light(unsigned target) {
  asm volatile("s_waitcnt vmcnt(0)" ::: "memory");  // drain own sc1 h-stores
  __syncthreads();
  if (threadIdx.x == 0)
    __hip_atomic_store(&g_arrive[blockIdx.x], target, __ATOMIC_RELAXED,
                       __HIP_MEMORY_SCOPE_AGENT);
  if (blockIdx.x == 0) {
    for (int i = threadIdx.x; i < LSTM_NWG; i += 256)
      while (__hip_atomic_load(&g_arrive[i], __ATOMIC_RELAXED,
                               __HIP_MEMORY_SCOPE_AGENT) < target)
        __builtin_amdgcn_s_sleep(1);
    __syncthreads();
    if (threadIdx.x == 0)
      __hip_atomic_store(&g_go, target, __ATOMIC_RELAXED,
                         __HIP_MEMORY_SCOPE_AGENT);
  }
  if (threadIdx.x == 0)
    while (__hip_atomic_load(&g_go, __ATOMIC_RELAXED,
                             __HIP_MEMORY_SCOPE_AGENT) < target)
      __builtin_amdgcn_s_sleep(1);
  __syncthreads();
  asm volatile("" ::: "memory");   // compiler barrier: no load hoisting
}

// ---------------- K1: init state + embedding gather ----------------
__global__ __launch_bounds__(512)
void k_init(const int* __restrict__ inputs, const float* __restrict__ h0in,
            const float* __restrict__ emb, float* __restrict__ ws) {
  const int g = blockIdx.x, tid = threadIdx.x;
  const int gid = g * 512 + tid;
  // Ping parity: layer-0 initial h in ping 0; layer-1 initial h in ping 1.
  if (gid < BH) {
    ws[O_H0 + gid]      = h0in[gid];
    ws[O_H1 + BH + gid] = h0in[BH + gid];
  }
#pragma unroll
  for (int r = 0; r < 4; ++r) {
    const int tb = g * 4 + r;
    ws[O_EMBS + (size_t)tb * H_ + tid] = emb[(size_t)inputs[tb] * H_ + tid];
  }
}

// ---------------- K2: persistent LSTM chain (round-7 validated) ----------
// 512 WGs x 256 threads, 2 WGs/CU. WG = (cell = g>>8, column pair cp = g&255).
// Weights LDS-resident (32 KB, loaded once, normal cached loads, re-read per
// MAC). Cross-stage h via sc1 loads/stores only; fence-free barrier.
// c-state in reduce-thread registers. VGPR fits the 128 cap with NO spill
// (rounds 9-13 lesson: every register-resident-weight variant spilled to
// scratch at GBs/dispatch; this shape is the proven no-spill design).
__global__ __launch_bounds__(256, 2)
void k_lstm(const float* __restrict__ W_ih, const float* __restrict__ W_hh,
            const float* __restrict__ b_ih, const float* __restrict__ b_hh,
            const float* __restrict__ c0in, float* __restrict__ out,
            float* __restrict__ ws) {
  const int g = blockIdx.x, tid = threadIdx.x;
  const int cell = g >> 8, cp = g & 255;
  float* EMBS = ws + O_EMBS;
  float* H0 = ws + O_H0;
  float* H1 = ws + O_H1;

  __shared__ __align__(16) float wlds[2][4][1024];   // [jj][gate][x|h] 32 KB
  __shared__ __align__(16) float stg0[32 * 132];     // staged H chunk (pad 132)
  __shared__ __align__(16) float stg1[32 * 132];
  __shared__ float red[64 * 17];

  // ---- one-time: stage this WG's weight rows into LDS (normal loads) ----
  {
    const float* Wih = W_ih + (size_t)cell * 4 * H_ * H_;
    const float* Whh = W_hh + (size_t)cell * 4 * H_ * H_;
#pragma unroll
    for (int l = 0; l < 8; ++l) {
      const int fidx = l * 256 + tid;     // float4 index 0..2047
      const int row = fidx >> 7;          // [jj(1)][gt(2)][h2(1)]
      const int c4 = fidx & 127;
      const int h2 = row & 1, gt = (row >> 1) & 3, jj = row >> 3;
      const float* src = (h2 ? Whh : Wih) + ((size_t)gt * H_ + cp * 2 + jj) * H_;
      *(float4*)&wlds[jj][gt][h2 * 512 + c4 * 4] = *(const float4*)(src + c4 * 4);
    }
  }
  // ---- one-time: bias sums + c-state into reduce-thread registers ----
  float creg = 0.f, bsum0 = 0.f, bsum1 = 0.f, bsum2 = 0.f, bsum3 = 0.f;
  if (tid < 64) {
    const int bb = tid & 31, j2 = tid >> 5;
    const int jo = cp * 2 + j2;
    creg = c0in[cell * BH + bb * H_ + jo];
    const float* bi = b_ih + (size_t)cell * 4 * H_;
    const float* bh = b_hh + (size_t)cell * 4 * H_;
    bsum0 = bi[0 * H_ + jo] + bh[0 * H_ + jo];
    bsum1 = bi[1 * H_ + jo] + bh[1 * H_ + jo];
    bsum2 = bi[2 * H_ + jo] + bh[2 * H_ + jo];
    bsum3 = bi[3 * H_ + jo] + bh[3 * H_ + jo];
  }
  __syncthreads();

  const int b = tid & 31, jj = (tid >> 5) & 1, ks = tid >> 6;
  const int lane = tid & 63;       // jj*32 + b

  unsigned bar = __hip_atomic_load(&g_go, __ATOMIC_RELAXED,
                                   __HIP_MEMORY_SCOPE_AGENT);

  for (int s = 0; s <= T_; ++s) {
    const int pi = s & 1, qi = pi ^ 1;
    const bool act = cell ? (s >= 1) : (s < T_);   // WG-uniform
    float a0 = 0.f, a1 = 0.f, a2 = 0.f, a3 = 0.f;

    if (act) {
      // ---- cell0 x-part: EMBS, normal cached loads (L2-hot, no fences) ----
      if (cell == 0) {
        const float* xs = EMBS + (size_t)s * BH + b * H_ + ks * 128;
        const float* wx0 = &wlds[jj][0][ks * 128];
        const float* wx1 = &wlds[jj][1][ks * 128];
        const float* wx2 = &wlds[jj][2][ks * 128];
        const float* wx3 = &wlds[jj][3][ks * 128];
#pragma unroll 8
        for (int k = 0; k < 128; k += 4) {
          const float4 x4 = *(const float4*)(xs + k);
          a0 += dot4(x4, *(const float4*)(wx0 + k));
          a1 += dot4(x4, *(const float4*)(wx1 + k));
          a2 += dot4(x4, *(const float4*)(wx2 + k));
          a3 += dot4(x4, *(const float4*)(wx3 + k));
        }
      }
      // ---- staged chunks: 4 x 128 k-cols of H0 (and H1 for cell1) ----
      const float* H0p = H0 + pi * BH;
      const float* H1p = H1 + pi * BH;
      for (int c = 0; c < 4; ++c) {
        {  // coalesced sc1 gather -> LDS (gather to regs first: loads pipeline)
          float v0[16];
#pragma unroll
          for (int i = 0; i < 16; ++i) {
            const int d = tid + i * 256;          // 0..4095
            const int bb2 = d >> 7, kk = d & 127;
            v0[i] = coh_load(H0p + bb2 * H_ + c * 128 + kk);
          }
          if (cell) {
            float v1[16];
#pragma unroll
            for (int i = 0; i < 16; ++i) {
              const int d = tid + i * 256;
              const int bb2 = d >> 7, kk = d & 127;
              v1[i] = coh_load(H1p + bb2 * H_ + c * 128 + kk);
            }
#pragma unroll
            for (int i = 0; i < 16; ++i) {
              const int d = tid + i * 256;
              const int bb2 = d >> 7, kk = d & 127;
              stg1[bb2 * 132 + kk] = v1[i];
            }
          }
#pragma unroll
          for (int i = 0; i < 16; ++i) {
            const int d = tid + i * 256;
            const int bb2 = d >> 7, kk = d & 127;
            stg0[bb2 * 132 + kk] = v0[i];
          }
        }
        __syncthreads();
        {  // compute this thread's k-subrange [c*128 + ks*32, +32)
          const int kb = c * 128 + ks * 32;
          if (cell) {  // x-part from staged H0
            const float* sd = &stg0[b * 132 + ks * 32];
            const float* w0 = &wlds[jj][0][kb];
            const float* w1 = &wlds[jj][1][kb];
            const float* w2 = &wlds[jj][2][kb];
            const float* w3 = &wlds[jj][3][kb];
#pragma unroll
            for (int k = 0; k < 32; k += 4) {
              const float4 x4 = *(const float4*)(sd + k);
              a0 += dot4(x4, *(const float4*)(w0 + k));
              a1 += dot4(x4, *(const float4*)(w1 + k));
              a2 += dot4(x4, *(const float4*)(w2 + k));
              a3 += dot4(x4, *(const float4*)(w3 + k));
            }
          }
          // h-part: cell0 from stg0 (H0), cell1 from stg1 (H1)
          const float* hd = cell ? &stg1[b * 132 + ks * 32]
                                 : &stg0[b * 132 + ks * 32];
          const float* u0 = &wlds[jj][0][512 + kb];
          const float* u1 = &wlds[jj][1][512 + kb];
          const float* u2 = &wlds[jj][2][512 + kb];
          const float* u3 = &wlds[jj][3][512 + kb];
#pragma unroll
          for (int k = 0; k < 32; k += 4) {
            const float4 h4 = *(const float4*)(hd + k);
            a0 += dot4(h4, *(const float4*)(u0 + k));
            a1 += dot4(h4, *(const float4*)(u1 + k));
            a2 += dot4(h4, *(const float4*)(u2 + k));
            a3 += dot4(h4, *(const float4*)(u3 + k));
          }
        }
        __syncthreads();
      }
      red[lane * 17 + 0 * 4 + ks] = a0;
      red[lane * 17 + 1 * 4 + ks] = a1;
      red[lane * 17 + 2 * 4 + ks] = a2;
      red[lane * 17 + 3 * 4 + ks] = a3;
    }
    __syncthreads();
    if (act && tid < 64) {
      const int bb = tid & 31, j2 = tid >> 5;
      const int jo = cp * 2 + j2;
      float gi = bsum0, gf = bsum1, gg = bsum2, go_ = bsum3;
#pragma unroll
      for (int k = 0; k < 4; ++k) {
        gi  += red[tid * 17 + 0 * 4 + k];
        gf  += red[tid * 17 + 1 * 4 + k];
        gg  += red[tid * 17 + 2 * 4 + k];
        go_ += red[tid * 17 + 3 * 4 + k];
      }
      const float cn = sigm(gf) * creg + sigm(gi) * tanhf(gg);
      const float hn = sigm(go_) * tanhf(cn);
      creg = cn;
      float* Hs = cell ? H1 : H0;
      __hip_atomic_store(&Hs[qi * BH + bb * H_ + jo], hn,
                         __ATOMIC_RELAXED, __HIP_MEMORY_SCOPE_AGENT);
      if (cell)  // stash h1(t) rows (XH) in out[t]
        out[((size_t)(s - 1) * B_ + bb) * H_ + jo] = hn;
      if (!cell && s == T_ - 1) {   // final h0/c0
        out[(size_t)T_ * BH + bb * H_ + jo]          = hn;
        out[(size_t)T_ * BH + 2 * BH + bb * H_ + jo] = cn;
      }
      if (cell && s == T_) {        // final h1/c1
        out[(size_t)T_ * BH + BH + bb * H_ + jo]     = hn;
        out[(size_t)T_ * BH + 3 * BH + bb * H_ + jo] = cn;
      }
    }
    if (s < T_) grid_barrier_light(++bar);
  }
}

// ---------------- tiled GEMM: C[m][n] = ep(A[m][:] . W[n][:] + bias[n]) ----
template<bool TANH, bool RES>
__global__ __launch_bounds__(256)
void k_gemm(const float* __restrict__ A1, const float* __restrict__ A2,
            const float* __restrict__ W, const float* __restrict__ bias,
            const float* __restrict__ res, float* __restrict__ C, int dualA) {
  const int bid = blockIdx.x, tid = threadIdx.x;
  const int m0 = (bid & 31) * 32, n0 = (bid >> 5) * 32;
  const int tx = tid & 15, ty = tid >> 4;
  const int lr = tid >> 5, lc = tid & 31;
  const int nsteps = dualA ? 32 : 16;
  const int Krow = dualA ? 1024 : 512;
  __shared__ __align__(16) float Asm[32 * 33];
  __shared__ __align__(16) float Bsm[32 * 34];
  float acc00 = 0.f, acc01 = 0.f, acc10 = 0.f, acc11 = 0.f;

  for (int kt = 0; kt < nsteps; ++kt) {
    const float* A = (kt < 16) ? A1 : A2;
    const int ka = (kt < 16) ? kt * 32 : (kt - 16) * 32;
    const int kb = kt * 32;
    __syncthreads();
#pragma unroll
    for (int i = 0; i < 4; ++i) {
      const int row = lr + i * 8;
      Asm[row * 33 + lc] = A[(size_t)(m0 + row) * 512 + ka + lc];
      Bsm[lc * 34 + row] = W[(size_t)(n0 + row) * Krow + kb + lc];
    }
    __syncthreads();
#pragma unroll 8
    for (int k = 0; k < 32; ++k) {
      const float a0 = Asm[(ty * 2) * 33 + k];
      const float a1 = Asm[(ty * 2 + 1) * 33 + k];
      const float2 bv = *(const float2*)&Bsm[k * 34 + tx * 2];
      acc00 += a0 * bv.x; acc01 += a0 * bv.y;
      acc10 += a1 * bv.x; acc11 += a1 * bv.y;
    }
  }
  const int n = n0 + tx * 2;
  const int m = m0 + ty * 2;
  const float bx = bias[n], by = bias[n + 1];
  float v00 = acc00 + bx, v01 = acc01 + by;
  float v10 = acc10 + bx, v11 = acc11 + by;
  if (TANH) { v00 = tanhf(v00); v01 = tanhf(v01); v10 = tanhf(v10); v11 = tanhf(v11); }
  if (RES) {
    v00 += res[(size_t)m * 512 + n];       v01 += res[(size_t)m * 512 + n + 1];
    v10 += res[(size_t)(m + 1) * 512 + n]; v11 += res[(size_t)(m + 1) * 512 + n + 1];
  }
  C[(size_t)m * 512 + n] = v00;            C[(size_t)m * 512 + n + 1] = v01;
  C[(size_t)(m + 1) * 512 + n] = v10;      C[(size_t)(m + 1) * 512 + n + 1] = v11;
}

// ---------------- K4: sigmoid-gated sweep, batched 4 t's per WG ------------
// grid 256 (bid = tc*32 + b; same-b WGs differ by 32 -> same XCD), block 512.
// Each WG reads ctx[b] once for 4 timesteps (4x L2-traffic cut vs per-t WGs).
__global__ __launch_bounds__(512)
void k_sweep_conv(const float* __restrict__ ctxc, const float* __restrict__ GC,
                  float* __restrict__ CTC) {
  const int bid = blockIdx.x, tid = threadIdx.x;
  const int b = bid & 31, tc = bid >> 5;
  const int w = tid >> 6, lane = tid & 63;
  float4 g0[4], g1[4];
#pragma unroll
  for (int tt = 0; tt < 4; ++tt) {
    const int m = (tc * 4 + tt) * B_ + b;
    const float* gl = GC + (size_t)m * H_ + lane * 8;
    g0[tt] = *(const float4*)gl;
    g1[tt] = *(const float4*)(gl + 4);
  }
  float4 a0[4], a1[4];
#pragma unroll
  for (int tt = 0; tt < 4; ++tt) {
    a0[tt] = make_float4(0, 0, 0, 0); a1[tt] = make_float4(0, 0, 0, 0);
  }
  const float* base = ctxc + (size_t)b * S_ * H_ + lane * 8;
  for (int i = 0; i < 64; ++i) {
    const int s = i * 8 + w;
    const float* xr = base + (size_t)s * H_;
    const float4 x0 = *(const float4*)(xr);
    const float4 x1 = *(const float4*)(xr + 4);
    float p[4];
#pragma unroll
    for (int tt = 0; tt < 4; ++tt)
      p[tt] = dot4(x0, g0[tt]) + dot4(x1, g1[tt]);
#pragma unroll
    for (int off = 32; off >= 1; off >>= 1) {
#pragma unroll
      for (int tt = 0; tt < 4; ++tt) p[tt] += __shfl_xor(p[tt], off, 64);
    }
#pragma unroll
    for (int tt = 0; tt < 4; ++tt) {
      const float wt = sigm(p[tt]);
      fma4(a0[tt], wt, x0); fma4(a1[tt], wt, x1);
    }
  }
  __shared__ __align__(16) float part[8 * 512];
#pragma unroll
  for (int tt = 0; tt < 4; ++tt) {
    __syncthreads();
    *(float4*)&part[w * 512 + lane * 8] = a0[tt];
    *(float4*)&part[w * 512 + lane * 8 + 4] = a1[tt];
    __syncthreads();
    float sum = 0.f;
#pragma unroll
    for (int w8 = 0; w8 < 8; ++w8) sum += part[w8 * 512 + tid];
    const int m = (tc * 4 + tt) * B_ + b;
    CTC[(size_t)m * H_ + tid] = sum;
  }
}

// ---------------- K7: online-softmax sweep, batched 4 t's per WG -----------
__global__ __launch_bounds__(512)
void k_sweep_att(const float* __restrict__ ctx, const float* __restrict__ GA,
                 float* __restrict__ CT) {
  const int bid = blockIdx.x, tid = threadIdx.x;
  const int b = bid & 31, tc = bid >> 5;
  const int w = tid >> 6, lane = tid & 63;
  float4 g0[4], g1[4];
#pragma unroll
  for (int tt = 0; tt < 4; ++tt) {
    const int m = (tc * 4 + tt) * B_ + b;
    const float* gl = GA + (size_t)m * H_ + lane * 8;
    g0[tt] = *(const float4*)gl;
    g1[tt] = *(const float4*)(gl + 4);
  }
  float4 a0[4], a1[4];
  float mx[4], lx[4];
#pragma unroll
  for (int tt = 0; tt < 4; ++tt) {
    a0[tt] = make_float4(0, 0, 0, 0); a1[tt] = make_float4(0, 0, 0, 0);
    mx[tt] = -1e30f; lx[tt] = 0.f;
  }
  const float* base = ctx + (size_t)b * S_ * H_ + lane * 8;
  for (int i = 0; i < 64; ++i) {
    const int s = i * 8 + w;
    const float* xr = base + (size_t)s * H_;
    const float4 x0 = *(const float4*)(xr);
    const float4 x1 = *(const float4*)(xr + 4);
    float p[4];
#pragma unroll
    for (int tt = 0; tt < 4; ++tt)
      p[tt] = dot4(x0, g0[tt]) + dot4(x1, g1[tt]);
#pragma unroll
    for (int off = 32; off >= 1; off >>= 1) {
#pragma unroll
      for (int tt = 0; tt < 4; ++tt) p[tt] += __shfl_xor(p[tt], off, 64);
    }
#pragma unroll
    for (int tt = 0; tt < 4; ++tt) {
      const float m2 = fmaxf(mx[tt], p[tt]);
      const float f = expf(mx[tt] - m2);
      const float e = expf(p[tt] - m2);
      lx[tt] = lx[tt] * f + e;
      scale_fma4(a0[tt], f, e, x0);
      scale_fma4(a1[tt], f, e, x1);
      mx[tt] = m2;
    }
  }
  __shared__ __align__(16) float part[8 * 512 + 16];
#pragma unroll
  for (int tt = 0; tt < 4; ++tt) {
    __syncthreads();
    *(float4*)&part[w * 512 + lane * 8] = a0[tt];
    *(float4*)&part[w * 512 + lane * 8 + 4] = a1[tt];
    if (lane == 0) { part[4096 + w * 2] = mx[tt]; part[4096 + w * 2 + 1] = lx[tt]; }
    __syncthreads();
    float M = part[4096];
#pragma unroll
    for (int w8 = 1; w8 < 8; ++w8) M = fmaxf(M, part[4096 + w8 * 2]);
    float L = 0.f, sum = 0.f;
#pragma unroll
    for (int w8 = 0; w8 < 8; ++w8) {
      const float f = expf(part[4096 + w8 * 2] - M);
      L   += f * part[4096 + w8 * 2 + 1];
      sum += f * part[w8 * 512 + tid];
    }
    const int m = (tc * 4 + tt) * B_ + b;
    CT[(size_t)m * H_ + tid] = sum / L;
  }
}

extern "C" void kernel_launch(void* const* d_in, const int* in_sizes, int n_in,
                              void* d_out, int out_size, void* d_ws, size_t ws_size,
                              hipStream_t stream) {
  const int*   inputs  = (const int*)d_in[0];
  const float* h0in    = (const float*)d_in[1];
  const float* c0in    = (const float*)d_in[2];
  const float* ctx     = (const float*)d_in[3];
  const float* ctxc    = (const float*)d_in[4];
  const float* emb     = (const float*)d_in[5];
  const float* W_ih    = (const float*)d_in[6];
  const float* W_hh    = (const float*)d_in[7];
  const float* b_ih    = (const float*)d_in[8];
  const float* b_hh    = (const float*)d_in[9];
  const float* Wi_att  = (const float*)d_in[10];
  const float* bi_att  = (const float*)d_in[11];
  const float* Wo_att  = (const float*)d_in[12];
  const float* bo_att  = (const float*)d_in[13];
  const float* Wi_conv = (const float*)d_in[14];
  const float* bi_conv = (const float*)d_in[15];
  const float* Wo_conv = (const float*)d_in[16];
  const float* bo_conv = (const float*)d_in[17];
  float* out = (float*)d_out;
  float* ws  = (float*)d_ws;

  float* GC  = ws + O_GC;    // gamma_conv, then gamma_att
  float* CTC = ws + O_CTC;   // ct_conv, then ct_att
  float* OCV = ws + O_OCV;   // out_conv

  k_init<<<dim3(256), dim3(512), 0, stream>>>(inputs, h0in, emb, ws);
  k_lstm<<<dim3(LSTM_NWG), dim3(256), 0, stream>>>(W_ih, W_hh, b_ih, b_hh,
                                                   c0in, out, ws);
  // gamma_conv = XH @ Wi_conv^T + bi_conv   (XH stashed in out)
  k_gemm<false, false><<<dim3(512), dim3(256), 0, stream>>>(
      out, nullptr, Wi_conv, bi_conv, nullptr, GC, 0);
  k_sweep_conv<<<dim3(256), dim3(512), 0, stream>>>(ctxc, GC, CTC);
  // out_conv = tanh([ct_c | XH] @ Wo_conv^T + bo_conv)
  k_gemm<true, false><<<dim3(512), dim3(256), 0, stream>>>(
      CTC, out, Wo_conv, bo_conv, nullptr, OCV, 1);
  // gamma_att = OCV @ Wi_att^T + bi_att
  k_gemm<false, false><<<dim3(512), dim3(256), 0, stream>>>(
      OCV, nullptr, Wi_att, bi_att, nullptr, GC, 0);
  k_sweep_att<<<dim3(256), dim3(512), 0, stream>>>(ctx, GC, CTC);
  // out = tanh([ct | OCV] @ Wo_att^T + bo_att) + OCV
  k_gemm<true, true><<<dim3(512), dim3(256), 0, stream>>>(
      CTC, OCV, Wo_att, bo_att, OCV, out, 1);
}

// Round 15
// 774.776 us; speedup vs baseline: 2.7939x; 1.0277x over previous
//
#include <hip/hip_runtime.h>
#include <math.h>

namespace {
constexpr int T_ = 32, B_ = 32, H_ = 512, S_ = 512;
constexpr int BH = B_ * H_;     // 16384
constexpr int LSTM_NWG = 512;
// ws float offsets
constexpr size_t O_EMBS = 0;                          // [T*B][H]
constexpr size_t O_H0   = O_EMBS + (size_t)T_ * BH;   // [2][BH]
constexpr size_t O_H1   = O_H0 + 2 * BH;              // [2][BH]
constexpr size_t O_GC   = O_H1 + 2 * BH;              // gamma [1024][512]
constexpr size_t O_CTC  = O_GC + (size_t)1024 * 512;  // ct
constexpr size_t O_OCV  = O_CTC + (size_t)1024 * 512; // out_conv
}

// Monotonic barrier state (zero-init at load, survives graph replays, immune
// to 0xAA ws poison). Used only by k_lstm.
__device__ unsigned g_arrive[LSTM_NWG] = {};
__device__ unsigned g_go = 0;

static __device__ __forceinline__ float sigm(float x) { return 1.0f / (1.0f + expf(-x)); }
static __device__ __forceinline__ float dot4(float4 a, float4 b) {
  return a.x * b.x + a.y * b.y + a.z * b.z + a.w * b.w;
}
static __device__ __forceinline__ void fma4(float4& a, float s, float4 x) {
  a.x += s * x.x; a.y += s * x.y; a.z += s * x.z; a.w += s * x.w;
}
static __device__ __forceinline__ void scale_fma4(float4& a, float f, float e, float4 x) {
  a.x = a.x * f + e * x.x; a.y = a.y * f + e * x.y;
  a.z = a.z * f + e * x.z; a.w = a.w * f + e * x.w;
}

static __device__ __forceinline__ unsigned long long coh_load_u64(const float* p) {
  return __hip_atomic_load((const unsigned long long*)p, __ATOMIC_RELAXED,
                           __HIP_MEMORY_SCOPE_AGENT);
}

// Fence-free grid barrier (validated round 7). Cross-WG data moves via sc1
// accesses that bypass L2; barrier needs only vmcnt drain + flag atomics.
static __device__ __forceinline__ void grid_barrier_light(unsigned target) {
  asm volatile("s_waitcnt vmcnt(0)" ::: "memory");  // drain own sc1 h-stores
  __syncthreads();
  if (threadIdx.x == 0)
    __hip_atomic_store(&g_arrive[blockIdx.x], target, __ATOMIC_RELAXED,
                       __HIP_MEMORY_SCOPE_AGENT);
  if (blockIdx.x == 0) {
    for (int i = threadIdx.x; i < LSTM_NWG; i += 256)
      while (__hip_atomic_load(&g_arrive[i], __ATOMIC_RELAXED,
                               __HIP_MEMORY_SCOPE_AGENT) < target)
        __builtin_amdgcn_s_sleep(1);
    __syncthreads();
    if (threadIdx.x == 0)
      __hip_atomic_store(&g_go, target, __ATOMIC_RELAXED,
                         __HIP_MEMORY_SCOPE_AGENT);
  }
  if (threadIdx.x == 0)
    while (__hip_atomic_load(&g_go, __ATOMIC_RELAXED,
                             __HIP_MEMORY_SCOPE_AGENT) < target)
      __builtin_amdgcn_s_sleep(1);
  __syncthreads();
  asm volatile("" ::: "memory");   // compiler barrier: no load hoisting
}

// ---------------- K1: init state + embedding gather ----------------
__global__ __launch_bounds__(512)
void k_init(const int* __restrict__ inputs, const float* __restrict__ h0in,
            const float* __restrict__ emb, float* __restrict__ ws) {
  const int g = blockIdx.x, tid = threadIdx.x;
  const int gid = g * 512 + tid;
  // Ping parity: layer-0 initial h in ping 0; layer-1 initial h in ping 1.
  if (gid < BH) {
    ws[O_H0 + gid]      = h0in[gid];
    ws[O_H1 + BH + gid] = h0in[BH + gid];
  }
#pragma unroll
  for (int r = 0; r < 4; ++r) {
    const int tb = g * 4 + r;
    ws[O_EMBS + (size_t)tb * H_ + tid] = emb[(size_t)inputs[tb] * H_ + tid];
  }
}

// ---------------- K2: persistent LSTM chain (round-7 core, pipelined) ------
// 512 WGs x 256 threads, 2 WGs/CU. WG = (cell = g>>8, column pair cp = g&255).
// Weights LDS-resident (32 KB, loaded once). Cross-stage h via sc1 only;
// fence-free barrier; c-state in reduce-thread registers.
// NEW vs round 14: chunk staging is software-pipelined — chunk c+1's u64
// coherent loads are issued right after chunk c's LDS writes, so their LLC
// latency (~600 cy) hides under MAC(c). u64 loads halve staging instr count.
// stg0 <- H0[pi] (both cells); stg1 <- H1[pi] (cell1 only).
__global__ __launch_bounds__(256, 2)
void k_lstm(const float* __restrict__ W_ih, const float* __restrict__ W_hh,
            const float* __restrict__ b_ih, const float* __restrict__ b_hh,
            const float* __restrict__ c0in, float* __restrict__ out,
            float* __restrict__ ws) {
  const int g = blockIdx.x, tid = threadIdx.x;
  const int cell = g >> 8, cp = g & 255;
  float* EMBS = ws + O_EMBS;
  float* H0 = ws + O_H0;
  float* H1 = ws + O_H1;

  __shared__ __align__(16) float wlds[2][4][1024];   // [jj][gate][x|h] 32 KB
  __shared__ __align__(16) float stg0[32 * 132];     // staged H chunk (pad 132)
  __shared__ __align__(16) float stg1[32 * 132];
  __shared__ float red[64 * 17];

  // ---- one-time: stage this WG's weight rows into LDS (normal loads) ----
  {
    const float* Wih = W_ih + (size_t)cell * 4 * H_ * H_;
    const float* Whh = W_hh + (size_t)cell * 4 * H_ * H_;
#pragma unroll
    for (int l = 0; l < 8; ++l) {
      const int fidx = l * 256 + tid;     // float4 index 0..2047
      const int row = fidx >> 7;          // [jj(1)][gt(2)][h2(1)]
      const int c4 = fidx & 127;
      const int h2 = row & 1, gt = (row >> 1) & 3, jj = row >> 3;
      const float* src = (h2 ? Whh : Wih) + ((size_t)gt * H_ + cp * 2 + jj) * H_;
      *(float4*)&wlds[jj][gt][h2 * 512 + c4 * 4] = *(const float4*)(src + c4 * 4);
    }
  }
  // ---- one-time: bias sums + c-state into reduce-thread registers ----
  float creg = 0.f, bsum0 = 0.f, bsum1 = 0.f, bsum2 = 0.f, bsum3 = 0.f;
  if (tid < 64) {
    const int bb = tid & 31, j2 = tid >> 5;
    const int jo = cp * 2 + j2;
    creg = c0in[cell * BH + bb * H_ + jo];
    const float* bi = b_ih + (size_t)cell * 4 * H_;
    const float* bh = b_hh + (size_t)cell * 4 * H_;
    bsum0 = bi[0 * H_ + jo] + bh[0 * H_ + jo];
    bsum1 = bi[1 * H_ + jo] + bh[1 * H_ + jo];
    bsum2 = bi[2 * H_ + jo] + bh[2 * H_ + jo];
    bsum3 = bi[3 * H_ + jo] + bh[3 * H_ + jo];
  }
  __syncthreads();

  const int b = tid & 31, jj = (tid >> 5) & 1, ks = tid >> 6;
  const int lane = tid & 63;       // jj*32 + b
  // staging indices (u64 pairs): 8 per operand-chunk per thread
  const int pidx = tid;            // pair base; p = pidx + i*256

  unsigned bar = __hip_atomic_load(&g_go, __ATOMIC_RELAXED,
                                   __HIP_MEMORY_SCOPE_AGENT);

  for (int s = 0; s <= T_; ++s) {
    const int pi = s & 1, qi = pi ^ 1;
    const bool act = cell ? (s >= 1) : (s < T_);   // WG-uniform
    float a0 = 0.f, a1 = 0.f, a2 = 0.f, a3 = 0.f;

    if (act) {
      // ---- cell0 x-part: EMBS, normal cached loads (L2-hot, no fences) ----
      if (cell == 0) {
        const float* xs = EMBS + (size_t)s * BH + b * H_ + ks * 128;
        const float* wx0 = &wlds[jj][0][ks * 128];
        const float* wx1 = &wlds[jj][1][ks * 128];
        const float* wx2 = &wlds[jj][2][ks * 128];
        const float* wx3 = &wlds[jj][3][ks * 128];
#pragma unroll 8
        for (int k = 0; k < 128; k += 4) {
          const float4 x4 = *(const float4*)(xs + k);
          a0 += dot4(x4, *(const float4*)(wx0 + k));
          a1 += dot4(x4, *(const float4*)(wx1 + k));
          a2 += dot4(x4, *(const float4*)(wx2 + k));
          a3 += dot4(x4, *(const float4*)(wx3 + k));
        }
      }
      // ---- pipelined staged chunks: 4 x 128 k-cols of H0 (and H1 cell1) ----
      const float* H0p = H0 + pi * BH;
      const float* H1p = H1 + pi * BH;
      unsigned long long pv0[8], pv1[8];
      // prologue: issue chunk-0 loads
#pragma unroll
      for (int i = 0; i < 8; ++i) {
        const int p = pidx + i * 256;           // pair idx 0..2047
        const int bb2 = p >> 6, kp = p & 63;
        pv0[i] = coh_load_u64(H0p + bb2 * H_ + kp * 2);
      }
      if (cell) {
#pragma unroll
        for (int i = 0; i < 8; ++i) {
          const int p = pidx + i * 256;
          const int bb2 = p >> 6, kp = p & 63;
          pv1[i] = coh_load_u64(H1p + bb2 * H_ + kp * 2);
        }
      }
      for (int c = 0; c < 4; ++c) {
        __syncthreads();   // prior MAC done reading stg
        // write chunk c (compiler inserts vmcnt wait here, after prior MAC)
#pragma unroll
        for (int i = 0; i < 8; ++i) {
          const int p = pidx + i * 256;
          const int bb2 = p >> 6, kp = p & 63;
          float2 f;
          f.x = __uint_as_float((unsigned)pv0[i]);
          f.y = __uint_as_float((unsigned)(pv0[i] >> 32));
          *(float2*)&stg0[bb2 * 132 + kp * 2] = f;
        }
        if (cell) {
#pragma unroll
          for (int i = 0; i < 8; ++i) {
            const int p = pidx + i * 256;
            const int bb2 = p >> 6, kp = p & 63;
            float2 f;
            f.x = __uint_as_float((unsigned)pv1[i]);
            f.y = __uint_as_float((unsigned)(pv1[i] >> 32));
            *(float2*)&stg1[bb2 * 132 + kp * 2] = f;
          }
        }
        // issue chunk c+1 loads (overlap with MAC below)
        if (c < 3) {
          const int co = (c + 1) * 128;
#pragma unroll
          for (int i = 0; i < 8; ++i) {
            const int p = pidx + i * 256;
            const int bb2 = p >> 6, kp = p & 63;
            pv0[i] = coh_load_u64(H0p + bb2 * H_ + co + kp * 2);
          }
          if (cell) {
#pragma unroll
            for (int i = 0; i < 8; ++i) {
              const int p = pidx + i * 256;
              const int bb2 = p >> 6, kp = p & 63;
              pv1[i] = coh_load_u64(H1p + bb2 * H_ + co + kp * 2);
            }
          }
        }
        __syncthreads();   // chunk c visible
        {  // MAC chunk c: this thread's k-subrange [c*128 + ks*32, +32)
          const int kb = c * 128 + ks * 32;
          if (cell) {  // x-part from staged H0
            const float* sd = &stg0[b * 132 + ks * 32];
            const float* w0 = &wlds[jj][0][kb];
            const float* w1 = &wlds[jj][1][kb];
            const float* w2 = &wlds[jj][2][kb];
            const float* w3 = &wlds[jj][3][kb];
#pragma unroll
            for (int k = 0; k < 32; k += 4) {
              const float4 x4 = *(const float4*)(sd + k);
              a0 += dot4(x4, *(const float4*)(w0 + k));
              a1 += dot4(x4, *(const float4*)(w1 + k));
              a2 += dot4(x4, *(const float4*)(w2 + k));
              a3 += dot4(x4, *(const float4*)(w3 + k));
            }
          }
          // h-part: cell0 from stg0 (H0), cell1 from stg1 (H1)
          const float* hd = cell ? &stg1[b * 132 + ks * 32]
                                 : &stg0[b * 132 + ks * 32];
          const float* u0 = &wlds[jj][0][512 + kb];
          const float* u1 = &wlds[jj][1][512 + kb];
          const float* u2 = &wlds[jj][2][512 + kb];
          const float* u3 = &wlds[jj][3][512 + kb];
#pragma unroll
          for (int k = 0; k < 32; k += 4) {
            const float4 h4 = *(const float4*)(hd + k);
            a0 += dot4(h4, *(const float4*)(u0 + k));
            a1 += dot4(h4, *(const float4*)(u1 + k));
            a2 += dot4(h4, *(const float4*)(u2 + k));
            a3 += dot4(h4, *(const float4*)(u3 + k));
          }
        }
      }
      __syncthreads();   // last MAC done before red write (red != stg, ok)
      red[lane * 17 + 0 * 4 + ks] = a0;
      red[lane * 17 + 1 * 4 + ks] = a1;
      red[lane * 17 + 2 * 4 + ks] = a2;
      red[lane * 17 + 3 * 4 + ks] = a3;
    }
    __syncthreads();
    if (act && tid < 64) {
      const int bb = tid & 31, j2 = tid >> 5;
      const int jo = cp * 2 + j2;
      float gi = bsum0, gf = bsum1, gg = bsum2, go_ = bsum3;
#pragma unroll
      for (int k = 0; k < 4; ++k) {
        gi  += red[tid * 17 + 0 * 4 + k];
        gf  += red[tid * 17 + 1 * 4 + k];
        gg  += red[tid * 17 + 2 * 4 + k];
        go_ += red[tid * 17 + 3 * 4 + k];
      }
      const float cn = sigm(gf) * creg + sigm(gi) * tanhf(gg);
      const float hn = sigm(go_) * tanhf(cn);
      creg = cn;
      float* Hs = cell ? H1 : H0;
      __hip_atomic_store(&Hs[qi * BH + bb * H_ + jo], hn,
                         __ATOMIC_RELAXED, __HIP_MEMORY_SCOPE_AGENT);
      if (cell)  // stash h1(t) rows (XH) in out[t]
        out[((size_t)(s - 1) * B_ + bb) * H_ + jo] = hn;
      if (!cell && s == T_ - 1) {   // final h0/c0
        out[(size_t)T_ * BH + bb * H_ + jo]          = hn;
        out[(size_t)T_ * BH + 2 * BH + bb * H_ + jo] = cn;
      }
      if (cell && s == T_) {        // final h1/c1
        out[(size_t)T_ * BH + BH + bb * H_ + jo]     = hn;
        out[(size_t)T_ * BH + 3 * BH + bb * H_ + jo] = cn;
      }
    }
    if (s < T_) grid_barrier_light(++bar);
  }
}

// ---------------- tiled GEMM: C[m][n] = ep(A[m][:] . W[n][:] + bias[n]) ----
template<bool TANH, bool RES>
__global__ __launch_bounds__(256)
void k_gemm(const float* __restrict__ A1, const float* __restrict__ A2,
            const float* __restrict__ W, const float* __restrict__ bias,
            const float* __restrict__ res, float* __restrict__ C, int dualA) {
  const int bid = blockIdx.x, tid = threadIdx.x;
  const int m0 = (bid & 31) * 32, n0 = (bid >> 5) * 32;
  const int tx = tid & 15, ty = tid >> 4;
  const int lr = tid >> 5, lc = tid & 31;
  const int nsteps = dualA ? 32 : 16;
  const int Krow = dualA ? 1024 : 512;
  __shared__ __align__(16) float Asm[32 * 33];
  __shared__ __align__(16) float Bsm[32 * 34];
  float acc00 = 0.f, acc01 = 0.f, acc10 = 0.f, acc11 = 0.f;

  for (int kt = 0; kt < nsteps; ++kt) {
    const float* A = (kt < 16) ? A1 : A2;
    const int ka = (kt < 16) ? kt * 32 : (kt - 16) * 32;
    const int kb = kt * 32;
    __syncthreads();
#pragma unroll
    for (int i = 0; i < 4; ++i) {
      const int row = lr + i * 8;
      Asm[row * 33 + lc] = A[(size_t)(m0 + row) * 512 + ka + lc];
      Bsm[lc * 34 + row] = W[(size_t)(n0 + row) * Krow + kb + lc];
    }
    __syncthreads();
#pragma unroll 8
    for (int k = 0; k < 32; ++k) {
      const float a0 = Asm[(ty * 2) * 33 + k];
      const float a1 = Asm[(ty * 2 + 1) * 33 + k];
      const float2 bv = *(const float2*)&Bsm[k * 34 + tx * 2];
      acc00 += a0 * bv.x; acc01 += a0 * bv.y;
      acc10 += a1 * bv.x; acc11 += a1 * bv.y;
    }
  }
  const int n = n0 + tx * 2;
  const int m = m0 + ty * 2;
  const float bx = bias[n], by = bias[n + 1];
  float v00 = acc00 + bx, v01 = acc01 + by;
  float v10 = acc10 + bx, v11 = acc11 + by;
  if (TANH) { v00 = tanhf(v00); v01 = tanhf(v01); v10 = tanhf(v10); v11 = tanhf(v11); }
  if (RES) {
    v00 += res[(size_t)m * 512 + n];       v01 += res[(size_t)m * 512 + n + 1];
    v10 += res[(size_t)(m + 1) * 512 + n]; v11 += res[(size_t)(m + 1) * 512 + n + 1];
  }
  C[(size_t)m * 512 + n] = v00;            C[(size_t)m * 512 + n + 1] = v01;
  C[(size_t)(m + 1) * 512 + n] = v10;      C[(size_t)(m + 1) * 512 + n + 1] = v11;
}

// ---------------- K4: sigmoid-gated sweep, batched 4 t's per WG ------------
// grid 256 (bid = tc*32 + b; same-b WGs differ by 32 -> same XCD), block 512.
// Each WG reads ctx[b] once for 4 timesteps (4x L2-traffic cut vs per-t WGs).
__global__ __launch_bounds__(512)
void k_sweep_conv(const float* __restrict__ ctxc, const float* __restrict__ GC,
                  float* __restrict__ CTC) {
  const int bid = blockIdx.x, tid = threadIdx.x;
  const int b = bid & 31, tc = bid >> 5;
  const int w = tid >> 6, lane = tid & 63;
  float4 g0[4], g1[4];
#pragma unroll
  for (int tt = 0; tt < 4; ++tt) {
    const int m = (tc * 4 + tt) * B_ + b;
    const float* gl = GC + (size_t)m * H_ + lane * 8;
    g0[tt] = *(const float4*)gl;
    g1[tt] = *(const float4*)(gl + 4);
  }
  float4 a0[4], a1[4];
#pragma unroll
  for (int tt = 0; tt < 4; ++tt) {
    a0[tt] = make_float4(0, 0, 0, 0); a1[tt] = make_float4(0, 0, 0, 0);
  }
  const float* base = ctxc + (size_t)b * S_ * H_ + lane * 8;
  for (int i = 0; i < 64; ++i) {
    const int s = i * 8 + w;
    const float* xr = base + (size_t)s * H_;
    const float4 x0 = *(const float4*)(xr);
    const float4 x1 = *(const float4*)(xr + 4);
    float p[4];
#pragma unroll
    for (int tt = 0; tt < 4; ++tt)
      p[tt] = dot4(x0, g0[tt]) + dot4(x1, g1[tt]);
#pragma unroll
    for (int off = 32; off >= 1; off >>= 1) {
#pragma unroll
      for (int tt = 0; tt < 4; ++tt) p[tt] += __shfl_xor(p[tt], off, 64);
    }
#pragma unroll
    for (int tt = 0; tt < 4; ++tt) {
      const float wt = sigm(p[tt]);
      fma4(a0[tt], wt, x0); fma4(a1[tt], wt, x1);
    }
  }
  __shared__ __align__(16) float part[8 * 512];
#pragma unroll
  for (int tt = 0; tt < 4; ++tt) {
    __syncthreads();
    *(float4*)&part[w * 512 + lane * 8] = a0[tt];
    *(float4*)&part[w * 512 + lane * 8 + 4] = a1[tt];
    __syncthreads();
    float sum = 0.f;
#pragma unroll
    for (int w8 = 0; w8 < 8; ++w8) sum += part[w8 * 512 + tid];
    const int m = (tc * 4 + tt) * B_ + b;
    CTC[(size_t)m * H_ + tid] = sum;
  }
}

// ---------------- K7: online-softmax sweep, batched 4 t's per WG -----------
__global__ __launch_bounds__(512)
void k_sweep_att(const float* __restrict__ ctx, const float* __restrict__ GA,
                 float* __restrict__ CT) {
  const int bid = blockIdx.x, tid = threadIdx.x;
  const int b = bid & 31, tc = bid >> 5;
  const int w = tid >> 6, lane = tid & 63;
  float4 g0[4], g1[4];
#pragma unroll
  for (int tt = 0; tt < 4; ++tt) {
    const int m = (tc * 4 + tt) * B_ + b;
    const float* gl = GA + (size_t)m * H_ + lane * 8;
    g0[tt] = *(const float4*)gl;
    g1[tt] = *(const float4*)(gl + 4);
  }
  float4 a0[4], a1[4];
  float mx[4], lx[4];
#pragma unroll
  for (int tt = 0; tt < 4; ++tt) {
    a0[tt] = make_float4(0, 0, 0, 0); a1[tt] = make_float4(0, 0, 0, 0);
    mx[tt] = -1e30f; lx[tt] = 0.f;
  }
  const float* base = ctx + (size_t)b * S_ * H_ + lane * 8;
  for (int i = 0; i < 64; ++i) {
    const int s = i * 8 + w;
    const float* xr = base + (size_t)s * H_;
    const float4 x0 = *(const float4*)(xr);
    const float4 x1 = *(const float4*)(xr + 4);
    float p[4];
#pragma unroll
    for (int tt = 0; tt < 4; ++tt)
      p[tt] = dot4(x0, g0[tt]) + dot4(x1, g1[tt]);
#pragma unroll
    for (int off = 32; off >= 1; off >>= 1) {
#pragma unroll
      for (int tt = 0; tt < 4; ++tt) p[tt] += __shfl_xor(p[tt], off, 64);
    }
#pragma unroll
    for (int tt = 0; tt < 4; ++tt) {
      const float m2 = fmaxf(mx[tt], p[tt]);
      const float f = expf(mx[tt] - m2);
      const float e = expf(p[tt] - m2);
      lx[tt] = lx[tt] * f + e;
      scale_fma4(a0[tt], f, e, x0);
      scale_fma4(a1[tt], f, e, x1);
      mx[tt] = m2;
    }
  }
  __shared__ __align__(16) float part[8 * 512 + 16];
#pragma unroll
  for (int tt = 0; tt < 4; ++tt) {
    __syncthreads();
    *(float4*)&part[w * 512 + lane * 8] = a0[tt];
    *(float4*)&part[w * 512 + lane * 8 + 4] = a1[tt];
    if (lane == 0) { part[4096 + w * 2] = mx[tt]; part[4096 + w * 2 + 1] = lx[tt]; }
    __syncthreads();
    float M = part[4096];
#pragma unroll
    for (int w8 = 1; w8 < 8; ++w8) M = fmaxf(M, part[4096 + w8 * 2]);
    float L = 0.f, sum = 0.f;
#pragma unroll
    for (int w8 = 0; w8 < 8; ++w8) {
      const float f = expf(part[4096 + w8 * 2] - M);
      L   += f * part[4096 + w8 * 2 + 1];
      sum += f * part[w8 * 512 + tid];
    }
    const int m = (tc * 4 + tt) * B_ + b;
    CT[(size_t)m * H_ + tid] = sum / L;
  }
}

extern "C" void kernel_launch(void* const* d_in, const int* in_sizes, int n_in,
                              void* d_out, int out_size, void* d_ws, size_t ws_size,
                              hipStream_t stream) {
  const int*   inputs  = (const int*)d_in[0];
  const float* h0in    = (const float*)d_in[1];
  const float* c0in    = (const float*)d_in[2];
  const float* ctx     = (const float*)d_in[3];
  const float* ctxc    = (const float*)d_in[4];
  const float* emb     = (const float*)d_in[5];
  const float* W_ih    = (const float*)d_in[6];
  const float* W_hh    = (const float*)d_in[7];
  const float* b_ih    = (const float*)d_in[8];
  const float* b_hh    = (const float*)d_in[9];
  const float* Wi_att  = (const float*)d_in[10];
  const float* bi_att  = (const float*)d_in[11];
  const float* Wo_att  = (const float*)d_in[12];
  const float* bo_att  = (const float*)d_in[13];
  const float* Wi_conv = (const float*)d_in[14];
  const float* bi_conv = (const float*)d_in[15];
  const float* Wo_conv = (const float*)d_in[16];
  const float* bo_conv = (const float*)d_in[17];
  float* out = (float*)d_out;
  float* ws  = (float*)d_ws;

  float* GC  = ws + O_GC;    // gamma_conv, then gamma_att
  float* CTC = ws + O_CTC;   // ct_conv, then ct_att
  float* OCV = ws + O_OCV;   // out_conv

  k_init<<<dim3(256), dim3(512), 0, stream>>>(inputs, h0in, emb, ws);
  k_lstm<<<dim3(LSTM_NWG), dim3(256), 0, stream>>>(W_ih, W_hh, b_ih, b_hh,
                                                   c0in, out, ws);
  // gamma_conv = XH @ Wi_conv^T + bi_conv   (XH stashed in out)
  k_gemm<false, false><<<dim3(512), dim3(256), 0, stream>>>(
      out, nullptr, Wi_conv, bi_conv, nullptr, GC, 0);
  k_sweep_conv<<<dim3(256), dim3(512), 0, stream>>>(ctxc, GC, CTC);
  // out_conv = tanh([ct_c | XH] @ Wo_conv^T + bo_conv)
  k_gemm<true, false><<<dim3(512), dim3(256), 0, stream>>>(
      CTC, out, Wo_conv, bo_conv, nullptr, OCV, 1);
  // gamma_att = OCV @ Wi_att^T + bi_att
  k_gemm<false, false><<<dim3(512), dim3(256), 0, stream>>>(
      OCV, nullptr, Wi_att, bi_att, nullptr, GC, 0);
  k_sweep_att<<<dim3(256), dim3(512), 0, stream>>>(ctx, GC, CTC);
  // out = tanh([ct | OCV] @ Wo_att^T + bo_att) + OCV
  k_gemm<true, true><<<dim3(512), dim3(256), 0, stream>>>(
      CTC, OCV, Wo_att, bo_att, OCV, out, 1);
}